// Round 1
// baseline (2599.458 us; speedup 1.0000x reference)
//
#include <hip/hip_runtime.h>

#define BN_EPS 1e-5f

// ---------- setup kernels ----------
__global__ void k_fill1(float* __restrict__ p, int n) {
    int i = blockIdx.x * blockDim.x + threadIdx.x;
    if (i < n) p[i] = 1.0f;
}

__global__ void k_count(const int* __restrict__ dst, float* __restrict__ deg, int E) {
    int e = blockIdx.x * blockDim.x + threadIdx.x;
    if (e < E) atomicAdd(&deg[dst[e]], 1.0f);
}

__global__ void k_rsqrt_inplace(float* __restrict__ p, int n) {
    int i = blockIdx.x * blockDim.x + threadIdx.x;
    if (i < n) p[i] = rsqrtf(p[i]);
}

__global__ void k_wnorm(const int* __restrict__ src, const int* __restrict__ dst,
                        const float* __restrict__ dinv, float* __restrict__ w, int E) {
    int e = blockIdx.x * blockDim.x + threadIdx.x;
    if (e < E) w[e] = dinv[src[e]] * dinv[dst[e]];
}

// ---------- GEMM: H[n,F] = (X[n,K] * aff_a + aff_c) @ W[K,F] ----------
template<int K, int KC, int F, bool AFF>
__global__ void k_gemm(const float* __restrict__ X, const float* __restrict__ W,
                       const float* __restrict__ aff, float* __restrict__ H, int n) {
    constexpr int ROWS = 16;
    __shared__ float sW[KC * F];
    __shared__ float sX[ROWS * K];
    const int tid = threadIdx.x;
    const int ntiles = (n + ROWS - 1) / ROWS;
    for (int tile = blockIdx.x; tile < ntiles; tile += gridDim.x) {
        const int r0 = tile * ROWS;
        const int nr = min(ROWS, n - r0);
        __syncthreads();  // protect sX/sW from previous iteration's readers
        for (int i = tid; i < nr * K; i += F) {
            float v = X[r0 * K + i];
            if constexpr (AFF) { int kk = i % K; v = v * aff[kk] + aff[K + kk]; }
            sX[i] = v;
        }
        float acc[ROWS];
        #pragma unroll
        for (int r = 0; r < ROWS; ++r) acc[r] = 0.0f;
        for (int kc = 0; kc < K; kc += KC) {
            __syncthreads();
            for (int s2 = 0; s2 < KC; ++s2) sW[s2 * F + tid] = W[(kc + s2) * F + tid];
            __syncthreads();
            #pragma unroll 4
            for (int k2 = 0; k2 < KC; ++k2) {
                const float w = sW[k2 * F + tid];
                #pragma unroll
                for (int r = 0; r < ROWS; ++r)
                    acc[r] = fmaf(sX[r * K + kc + k2], w, acc[r]);
            }
        }
        for (int r = 0; r < nr; ++r) H[(r0 + r) * F + tid] = acc[r];
    }
}

// ---------- self-loop init: A = H * dinv^2 ----------
template<int LOGF>
__global__ void k_agg_init(const float* __restrict__ H, const float* __restrict__ dinv,
                           float* __restrict__ A, int total) {
    int i = blockIdx.x * blockDim.x + threadIdx.x;
    if (i < total) {
        float di = dinv[i >> LOGF];
        A[i] = H[i] * di * di;
    }
}

// ---------- edge scatter-add: A[dst] += H[src] * w[e] ----------
template<int LOGF>
__global__ void k_edge_agg(const int* __restrict__ src, const int* __restrict__ dst,
                           const float* __restrict__ w, const float* __restrict__ H,
                           float* __restrict__ A, unsigned total) {
    const unsigned stride = gridDim.x * blockDim.x;
    for (unsigned i = blockIdx.x * blockDim.x + threadIdx.x; i < total; i += stride) {
        const unsigned e = i >> LOGF;
        const unsigned f = i & ((1u << LOGF) - 1u);
        const unsigned s = (unsigned)src[e];
        const unsigned d = (unsigned)dst[e];
        atomicAdd(&A[(d << LOGF) + f], H[(s << LOGF) + f] * w[e]);
    }
}

// ---------- bias + ReLU (in place) + column sum/sumsq stats ----------
template<int F>
__global__ void k_post(float* __restrict__ A, const float* __restrict__ b,
                       float* __restrict__ sums, int n) {
    constexpr int RPB = 256 / F;
    __shared__ float red[512];
    const int t = threadIdx.x;
    const int f = t & (F - 1);
    const int ro = t / F;
    float ls = 0.0f, lq = 0.0f;
    for (int r = blockIdx.x * RPB + ro; r < n; r += gridDim.x * RPB) {
        float v = A[r * F + f] + b[f];
        v = fmaxf(v, 0.0f);
        A[r * F + f] = v;
        ls += v;
        lq += v * v;
    }
    red[t] = ls; red[256 + t] = lq;
    __syncthreads();
    for (int s = 128; s >= F; s >>= 1) {
        if (t < s) { red[t] += red[t + s]; red[256 + t] += red[256 + t + s]; }
        __syncthreads();
    }
    if (t < F) { atomicAdd(&sums[t], red[t]); atomicAdd(&sums[F + t], red[256 + t]); }
}

// ---------- BN fold: aff = [a = rsqrt(var+eps)*g, c = be - mean*a] ----------
__global__ void k_bnprep(const float* __restrict__ sums, const float* __restrict__ g,
                         const float* __restrict__ be, float* __restrict__ aff,
                         int F, float invn) {
    int f = threadIdx.x;
    if (f < F) {
        float mean = sums[f] * invn;
        float var = sums[F + f] * invn - mean * mean;
        float a = rsqrtf(var + BN_EPS) * g[f];
        aff[f] = a;
        aff[F + f] = be[f] - mean * a;
    }
}

// ---------- final 64->2 GEMM with input affine ----------
__global__ void k_gemm4(const float* __restrict__ X, const float* __restrict__ W,
                        const float* __restrict__ aff, float* __restrict__ H, int n) {
    int i = blockIdx.x * blockDim.x + threadIdx.x;
    if (i >= n) return;
    float a0 = 0.0f, a1 = 0.0f;
    #pragma unroll 8
    for (int k = 0; k < 64; ++k) {
        float v = X[i * 64 + k] * aff[k] + aff[64 + k];
        a0 = fmaf(v, W[2 * k], a0);
        a1 = fmaf(v, W[2 * k + 1], a1);
    }
    H[2 * i] = a0;
    H[2 * i + 1] = a1;
}

// ---------- bias + log_softmax over 2 classes ----------
__global__ void k_final(const float* __restrict__ A, const float* __restrict__ b,
                        float* __restrict__ out, int n) {
    int i = blockIdx.x * blockDim.x + threadIdx.x;
    if (i >= n) return;
    float v0 = A[2 * i] + b[0];
    float v1 = A[2 * i + 1] + b[1];
    float m = fmaxf(v0, v1);
    float l = logf(expf(v0 - m) + expf(v1 - m)) + m;
    out[2 * i] = v0 - l;
    out[2 * i + 1] = v1 - l;
}

extern "C" void kernel_launch(void* const* d_in, const int* in_sizes, int n_in,
                              void* d_out, int out_size, void* d_ws, size_t ws_size,
                              hipStream_t stream) {
    const float* x   = (const float*)d_in[0];
    const int*   ei  = (const int*)d_in[1];
    const float* W1  = (const float*)d_in[2];
    const float* b1  = (const float*)d_in[3];
    const float* g1  = (const float*)d_in[4];
    const float* be1 = (const float*)d_in[5];
    const float* W2  = (const float*)d_in[6];
    const float* b2  = (const float*)d_in[7];
    const float* g2  = (const float*)d_in[8];
    const float* be2 = (const float*)d_in[9];
    const float* W3  = (const float*)d_in[10];
    const float* b3  = (const float*)d_in[11];
    const float* g3  = (const float*)d_in[12];
    const float* be3 = (const float*)d_in[13];
    const float* W4  = (const float*)d_in[14];
    const float* b4  = (const float*)d_in[15];
    float* out = (float*)d_out;

    const int N = in_sizes[0] / 24;
    const int E = in_sizes[1] / 2;
    const int* srcI = ei;
    const int* dstI = ei + E;

    float* ws   = (float*)d_ws;
    float* dinv = ws;                       // N
    float* wn   = dinv + N;                 // E
    float* H    = wn + E;                   // N*128
    float* A    = H + (size_t)N * 128;      // N*128
    float* S    = A + (size_t)N * 128;      // 1280 stats floats
    float* sums1 = S,        *aff1 = S + 256;
    float* sums2 = S + 512,  *aff2 = S + 768;
    float* sums3 = S + 1024, *aff3 = S + 1152;

    hipMemsetAsync(S, 0, 1280 * sizeof(float), stream);

    const int TB = 256;
    k_fill1<<<(N + TB - 1) / TB, TB, 0, stream>>>(dinv, N);
    k_count<<<(E + TB - 1) / TB, TB, 0, stream>>>(dstI, dinv, E);
    k_rsqrt_inplace<<<(N + TB - 1) / TB, TB, 0, stream>>>(dinv, N);
    k_wnorm<<<(E + TB - 1) / TB, TB, 0, stream>>>(srcI, dstI, dinv, wn, E);

    const int gtiles = (N + 15) / 16;

    // ----- layer 1: 24 -> 128 -----
    k_gemm<24, 24, 128, false><<<gtiles, 128, 0, stream>>>(x, W1, nullptr, H, N);
    k_agg_init<7><<<(N * 128 + TB - 1) / TB, TB, 0, stream>>>(H, dinv, A, N * 128);
    k_edge_agg<7><<<8192, TB, 0, stream>>>(srcI, dstI, wn, H, A, (unsigned)E * 128u);
    k_post<128><<<512, TB, 0, stream>>>(A, b1, sums1, N);
    k_bnprep<<<1, 128, 0, stream>>>(sums1, g1, be1, aff1, 128, 1.0f / (float)N);

    // ----- layer 2: 128 -> 128 -----
    k_gemm<128, 64, 128, true><<<gtiles, 128, 0, stream>>>(A, W2, aff1, H, N);
    k_agg_init<7><<<(N * 128 + TB - 1) / TB, TB, 0, stream>>>(H, dinv, A, N * 128);
    k_edge_agg<7><<<8192, TB, 0, stream>>>(srcI, dstI, wn, H, A, (unsigned)E * 128u);
    k_post<128><<<512, TB, 0, stream>>>(A, b2, sums2, N);
    k_bnprep<<<1, 128, 0, stream>>>(sums2, g2, be2, aff2, 128, 1.0f / (float)N);

    // ----- layer 3: 128 -> 64 -----
    k_gemm<128, 64, 64, true><<<gtiles, 64, 0, stream>>>(A, W3, aff2, H, N);
    k_agg_init<6><<<(N * 64 + TB - 1) / TB, TB, 0, stream>>>(H, dinv, A, N * 64);
    k_edge_agg<6><<<8192, TB, 0, stream>>>(srcI, dstI, wn, H, A, (unsigned)E * 64u);
    k_post<64><<<512, TB, 0, stream>>>(A, b3, sums3, N);
    k_bnprep<<<1, 64, 0, stream>>>(sums3, g3, be3, aff3, 64, 1.0f / (float)N);

    // ----- layer 4: 64 -> 2, log_softmax -----
    k_gemm4<<<(N + TB - 1) / TB, TB, 0, stream>>>(A, W4, aff3, H, N);
    k_agg_init<1><<<(N * 2 + TB - 1) / TB, TB, 0, stream>>>(H, dinv, A, N * 2);
    k_edge_agg<1><<<2048, TB, 0, stream>>>(srcI, dstI, wn, H, A, (unsigned)E * 2u);
    k_final<<<(N + TB - 1) / TB, TB, 0, stream>>>(A, b4, out, N);
}

// Round 2
// 1458.348 us; speedup vs baseline: 1.7825x; 1.7825x over previous
//
#include <hip/hip_runtime.h>

#define BN_EPS 1e-5f

// ---------- degree count (int) ----------
__global__ void k_zero_i(int* __restrict__ p, int n) {
    int i = blockIdx.x * blockDim.x + threadIdx.x;
    if (i < n) p[i] = 0;
}

__global__ void k_count(const int* __restrict__ dst, int* __restrict__ cnt, int E) {
    int e = blockIdx.x * blockDim.x + threadIdx.x;
    if (e < E) atomicAdd(&cnt[dst[e]], 1);
}

__global__ void k_dinv(const int* __restrict__ cnt, float* __restrict__ dinv, int n) {
    int i = blockIdx.x * blockDim.x + threadIdx.x;
    if (i < n) dinv[i] = rsqrtf((float)(cnt[i] + 1));   // +1 self loop
}

// ---------- exclusive scan (two-level, N <= 1024*1024) ----------
__global__ void k_scan1(const int* __restrict__ cnt, int* __restrict__ rs,
                        int* __restrict__ bsum, int n) {
    __shared__ int sh[1024];
    const int t = threadIdx.x;
    const int gid = blockIdx.x * 1024 + t;
    int v = (gid < n) ? cnt[gid] : 0;
    sh[t] = v;
    __syncthreads();
    for (int off = 1; off < 1024; off <<= 1) {
        int u = (t >= off) ? sh[t - off] : 0;
        __syncthreads();
        sh[t] += u;
        __syncthreads();
    }
    if (gid < n) rs[gid] = sh[t] - v;       // exclusive
    if (t == 1023) bsum[blockIdx.x] = sh[1023];
}

__global__ void k_scan2(int* __restrict__ bsum, int nb) {
    __shared__ int sh[1024];
    const int t = threadIdx.x;
    int v = (t < nb) ? bsum[t] : 0;
    sh[t] = v;
    __syncthreads();
    for (int off = 1; off < 1024; off <<= 1) {
        int u = (t >= off) ? sh[t - off] : 0;
        __syncthreads();
        sh[t] += u;
        __syncthreads();
    }
    if (t < nb) bsum[t] = sh[t] - v;        // exclusive
}

__global__ void k_scan3(int* __restrict__ rs, int* __restrict__ cur,
                        const int* __restrict__ bsum, int n) {
    int i = blockIdx.x * blockDim.x + threadIdx.x;
    if (i < n) {
        int v = rs[i] + bsum[i >> 10];
        rs[i] = v;
        cur[i] = v;
    }
}

// ---------- CSR fill: csrc[pos] = src (order within row arbitrary) ----------
__global__ void k_fill(const int* __restrict__ src, const int* __restrict__ dst,
                       int* __restrict__ cur, int* __restrict__ csrc, int E) {
    int e = blockIdx.x * blockDim.x + threadIdx.x;
    if (e < E) {
        int pos = atomicAdd(&cur[dst[e]], 1);
        csrc[pos] = src[e];
    }
}

// ---------- GEMM: H[n,F] = (X[n,K] * aff_a + aff_c) @ W[K,F] ----------
template<int K, int KC, int F, bool AFF>
__global__ void k_gemm(const float* __restrict__ X, const float* __restrict__ W,
                       const float* __restrict__ aff, float* __restrict__ H, int n) {
    constexpr int ROWS = 16;
    __shared__ float sW[KC * F];
    __shared__ float sX[ROWS * K];
    const int tid = threadIdx.x;
    const int ntiles = (n + ROWS - 1) / ROWS;
    for (int tile = blockIdx.x; tile < ntiles; tile += gridDim.x) {
        const int r0 = tile * ROWS;
        const int nr = min(ROWS, n - r0);
        __syncthreads();
        for (int i = tid; i < nr * K; i += F) {
            float v = X[r0 * K + i];
            if constexpr (AFF) { int kk = i % K; v = v * aff[kk] + aff[K + kk]; }
            sX[i] = v;
        }
        float acc[ROWS];
        #pragma unroll
        for (int r = 0; r < ROWS; ++r) acc[r] = 0.0f;
        for (int kc = 0; kc < K; kc += KC) {
            __syncthreads();
            for (int s2 = 0; s2 < KC; ++s2) sW[s2 * F + tid] = W[(kc + s2) * F + tid];
            __syncthreads();
            #pragma unroll 4
            for (int k2 = 0; k2 < KC; ++k2) {
                const float w = sW[k2 * F + tid];
                #pragma unroll
                for (int r = 0; r < ROWS; ++r)
                    acc[r] = fmaf(sX[r * K + kc + k2], w, acc[r]);
            }
        }
        for (int r = 0; r < nr; ++r) H[(r0 + r) * F + tid] = acc[r];
    }
}

// ---------- CSR gather aggregation, fused self-loop + bias + ReLU + stats ----------
// block = F threads; each block grid-strides over nodes. A[d,f] = relu(dinv[d]*
// (H[d,f]*dinv[d] + sum_j H[src_j,f]*dinv[src_j]) + b[f]); col stats accumulated.
template<int F>
__global__ void k_aggf(const float* __restrict__ H, const int* __restrict__ rs,
                       const int* __restrict__ rend, const int* __restrict__ csrc,
                       const float* __restrict__ dinv, const float* __restrict__ b,
                       float* __restrict__ A, float* __restrict__ sums, int n) {
    const int f = threadIdx.x;
    const float bf = b[f];
    float ls = 0.0f, lq = 0.0f;
    for (int d = blockIdx.x; d < n; d += gridDim.x) {
        const int beg = rs[d];
        const int end = rend[d];
        const float di = dinv[d];
        float acc = H[(size_t)d * F + f] * di;    // self loop (x di again below)
        int j = beg;
        for (; j + 1 < end; j += 2) {
            int s0 = csrc[j], s1 = csrc[j + 1];
            float w0 = dinv[s0], w1 = dinv[s1];
            float h0 = H[(size_t)s0 * F + f], h1 = H[(size_t)s1 * F + f];
            acc = fmaf(h0, w0, acc);
            acc = fmaf(h1, w1, acc);
        }
        if (j < end) {
            int s = csrc[j];
            acc = fmaf(H[(size_t)s * F + f], dinv[s], acc);
        }
        float v = fmaxf(fmaf(acc, di, bf), 0.0f);
        A[(size_t)d * F + f] = v;
        ls += v;
        lq += v * v;
    }
    atomicAdd(&sums[f], ls);
    atomicAdd(&sums[F + f], lq);
}

// ---------- BN fold: aff = [a = rsqrt(var+eps)*g, c = be - mean*a] ----------
__global__ void k_bnprep(const float* __restrict__ sums, const float* __restrict__ g,
                         const float* __restrict__ be, float* __restrict__ aff,
                         int F, float invn) {
    int f = threadIdx.x;
    if (f < F) {
        float mean = sums[f] * invn;
        float var = sums[F + f] * invn - mean * mean;
        float a = rsqrtf(var + BN_EPS) * g[f];
        aff[f] = a;
        aff[F + f] = be[f] - mean * a;
    }
}

// ---------- final 64->2 GEMM with input affine ----------
__global__ void k_gemm4(const float* __restrict__ X, const float* __restrict__ W,
                        const float* __restrict__ aff, float* __restrict__ H, int n) {
    int i = blockIdx.x * blockDim.x + threadIdx.x;
    if (i >= n) return;
    float a0 = 0.0f, a1 = 0.0f;
    #pragma unroll 8
    for (int k = 0; k < 64; ++k) {
        float v = X[i * 64 + k] * aff[k] + aff[64 + k];
        a0 = fmaf(v, W[2 * k], a0);
        a1 = fmaf(v, W[2 * k + 1], a1);
    }
    H[2 * i] = a0;
    H[2 * i + 1] = a1;
}

// ---------- final aggregation (F=2) + bias + log_softmax, 1 thread/node ----------
__global__ void k_last(const float* __restrict__ H, const int* __restrict__ rs,
                       const int* __restrict__ rend, const int* __restrict__ csrc,
                       const float* __restrict__ dinv, const float* __restrict__ b,
                       float* __restrict__ out, int n) {
    int d = blockIdx.x * blockDim.x + threadIdx.x;
    if (d >= n) return;
    const float di = dinv[d];
    float a0 = H[2 * d] * di, a1 = H[2 * d + 1] * di;
    const int beg = rs[d], end = rend[d];
    for (int j = beg; j < end; ++j) {
        int s = csrc[j];
        float w = dinv[s];
        a0 = fmaf(H[2 * s], w, a0);
        a1 = fmaf(H[2 * s + 1], w, a1);
    }
    float v0 = fmaf(a0, di, b[0]);
    float v1 = fmaf(a1, di, b[1]);
    float m = fmaxf(v0, v1);
    float l = logf(expf(v0 - m) + expf(v1 - m)) + m;
    out[2 * d] = v0 - l;
    out[2 * d + 1] = v1 - l;
}

extern "C" void kernel_launch(void* const* d_in, const int* in_sizes, int n_in,
                              void* d_out, int out_size, void* d_ws, size_t ws_size,
                              hipStream_t stream) {
    const float* x   = (const float*)d_in[0];
    const int*   ei  = (const int*)d_in[1];
    const float* W1  = (const float*)d_in[2];
    const float* b1  = (const float*)d_in[3];
    const float* g1  = (const float*)d_in[4];
    const float* be1 = (const float*)d_in[5];
    const float* W2  = (const float*)d_in[6];
    const float* b2  = (const float*)d_in[7];
    const float* g2  = (const float*)d_in[8];
    const float* be2 = (const float*)d_in[9];
    const float* W3  = (const float*)d_in[10];
    const float* b3  = (const float*)d_in[11];
    const float* g3  = (const float*)d_in[12];
    const float* be3 = (const float*)d_in[13];
    const float* W4  = (const float*)d_in[14];
    const float* b4  = (const float*)d_in[15];
    float* out = (float*)d_out;

    const int N = in_sizes[0] / 24;
    const int E = in_sizes[1] / 2;
    const int* srcI = ei;
    const int* dstI = ei + E;

    // ---- workspace carve ----
    int* cnt   = (int*)d_ws;                 // N
    int* rs    = cnt + N;                    // N  (row start)
    int* cur   = rs + N;                     // N  (fill cursor -> row end)
    int* csrc  = cur + N;                    // E  (CSR src ids)
    int* bsum  = csrc + E;                   // 1024 (scan partials)
    float* dinv = (float*)(bsum + 1024);     // N
    float* H    = dinv + N;                  // N*128
    float* A    = H + (size_t)N * 128;       // N*128
    float* S    = A + (size_t)N * 128;       // 1280 stats
    float* sums1 = S,        *aff1 = S + 256;
    float* sums2 = S + 512,  *aff2 = S + 768;
    float* sums3 = S + 1024, *aff3 = S + 1152;

    hipMemsetAsync(S, 0, 1280 * sizeof(float), stream);

    const int TB = 256;
    const int nb = (N + 1023) / 1024;

    // ---- CSR build + dinv ----
    k_zero_i<<<(N + TB - 1) / TB, TB, 0, stream>>>(cnt, N);
    k_count<<<(E + TB - 1) / TB, TB, 0, stream>>>(dstI, cnt, E);
    k_dinv<<<(N + TB - 1) / TB, TB, 0, stream>>>(cnt, dinv, N);
    k_scan1<<<nb, 1024, 0, stream>>>(cnt, rs, bsum, N);
    k_scan2<<<1, 1024, 0, stream>>>(bsum, nb);
    k_scan3<<<(N + TB - 1) / TB, TB, 0, stream>>>(rs, cur, bsum, N);
    k_fill<<<(E + TB - 1) / TB, TB, 0, stream>>>(srcI, dstI, cur, csrc, E);
    // after k_fill, cur[d] == row end

    const int gtiles = (N + 15) / 16;

    // ----- layer 1: 24 -> 128 -----
    k_gemm<24, 24, 128, false><<<gtiles, 128, 0, stream>>>(x, W1, nullptr, H, N);
    k_aggf<128><<<4096, 128, 0, stream>>>(H, rs, cur, csrc, dinv, b1, A, sums1, N);
    k_bnprep<<<1, 128, 0, stream>>>(sums1, g1, be1, aff1, 128, 1.0f / (float)N);

    // ----- layer 2: 128 -> 128 -----
    k_gemm<128, 64, 128, true><<<gtiles, 128, 0, stream>>>(A, W2, aff1, H, N);
    k_aggf<128><<<4096, 128, 0, stream>>>(H, rs, cur, csrc, dinv, b2, A, sums2, N);
    k_bnprep<<<1, 128, 0, stream>>>(sums2, g2, be2, aff2, 128, 1.0f / (float)N);

    // ----- layer 3: 128 -> 64 -----
    k_gemm<128, 64, 64, true><<<gtiles, 64, 0, stream>>>(A, W3, aff2, H, N);
    k_aggf<64><<<4096, 64, 0, stream>>>(H, rs, cur, csrc, dinv, b3, A, sums3, N);
    k_bnprep<<<1, 64, 0, stream>>>(sums3, g3, be3, aff3, 64, 1.0f / (float)N);

    // ----- layer 4: 64 -> 2, log_softmax -----
    k_gemm4<<<(N + TB - 1) / TB, TB, 0, stream>>>(A, W4, aff3, H, N);
    k_last<<<(N + TB - 1) / TB, TB, 0, stream>>>(H, rs, cur, csrc, dinv, b4, out, N);
}

// Round 3
// 969.335 us; speedup vs baseline: 2.6817x; 1.5045x over previous
//
#include <hip/hip_runtime.h>

#define BN_EPS 1e-5f

// ---------- degree count (int) ----------
__global__ void k_zero_i(int* __restrict__ p, int n) {
    int i = blockIdx.x * blockDim.x + threadIdx.x;
    if (i < n) p[i] = 0;
}

__global__ void k_count(const int* __restrict__ dst, int* __restrict__ cnt, int E) {
    int e = blockIdx.x * blockDim.x + threadIdx.x;
    if (e < E) atomicAdd(&cnt[dst[e]], 1);
}

__global__ void k_dinv(const int* __restrict__ cnt, float* __restrict__ dinv, int n) {
    int i = blockIdx.x * blockDim.x + threadIdx.x;
    if (i < n) dinv[i] = rsqrtf((float)(cnt[i] + 1));   // +1 self loop
}

// ---------- exclusive scan (two-level, N <= 1024*1024) ----------
__global__ void k_scan1(const int* __restrict__ cnt, int* __restrict__ rs,
                        int* __restrict__ bsum, int n) {
    __shared__ int sh[1024];
    const int t = threadIdx.x;
    const int gid = blockIdx.x * 1024 + t;
    int v = (gid < n) ? cnt[gid] : 0;
    sh[t] = v;
    __syncthreads();
    for (int off = 1; off < 1024; off <<= 1) {
        int u = (t >= off) ? sh[t - off] : 0;
        __syncthreads();
        sh[t] += u;
        __syncthreads();
    }
    if (gid < n) rs[gid] = sh[t] - v;       // exclusive
    if (t == 1023) bsum[blockIdx.x] = sh[1023];
}

__global__ void k_scan2(int* __restrict__ bsum, int nb) {
    __shared__ int sh[1024];
    const int t = threadIdx.x;
    int v = (t < nb) ? bsum[t] : 0;
    sh[t] = v;
    __syncthreads();
    for (int off = 1; off < 1024; off <<= 1) {
        int u = (t >= off) ? sh[t - off] : 0;
        __syncthreads();
        sh[t] += u;
        __syncthreads();
    }
    if (t < nb) bsum[t] = sh[t] - v;        // exclusive
}

__global__ void k_scan3(int* __restrict__ rs, int* __restrict__ cur,
                        const int* __restrict__ bsum, int n) {
    int i = blockIdx.x * blockDim.x + threadIdx.x;
    if (i < n) {
        int v = rs[i] + bsum[i >> 10];
        rs[i] = v;
        cur[i] = v;
    }
}

// ---------- CSR fill: csrc[pos] = src (order within row arbitrary) ----------
__global__ void k_fill(const int* __restrict__ src, const int* __restrict__ dst,
                       int* __restrict__ cur, int* __restrict__ csrc, int E) {
    int e = blockIdx.x * blockDim.x + threadIdx.x;
    if (e < E) {
        int pos = atomicAdd(&cur[dst[e]], 1);
        csrc[pos] = src[e];
    }
}

// ---------- GEMM v2: H[n,F] = (X[n,K]*aff_a + aff_c) @ W[K,F] ----------
// 256 threads. W resident in LDS for block lifetime; X staged in TR-row tiles.
// Thread micro-tile: RT rows x 4 cols; float4 LDS reads both operands.
template<int K, int F, int RT, bool AFF>
__global__ __launch_bounds__(256) void k_gemm2(const float* __restrict__ X,
        const float* __restrict__ W, const float* __restrict__ aff,
        float* __restrict__ H, int n) {
    constexpr int COLG = F / 4;          // column groups (4 cols each)
    constexpr int ROWG = 256 / COLG;     // row groups
    constexpr int TR = ROWG * RT;        // rows per tile
    __shared__ float sW[K * F];
    __shared__ float sX[TR * K];
    const int tid = threadIdx.x;
    const int tx = tid % COLG;
    const int ty = tid / COLG;

    // stage W once per block
    for (int i = tid * 4; i < K * F; i += 1024)
        *(float4*)&sW[i] = *(const float4*)&W[i];

    const int ntiles = (n + TR - 1) / TR;
    for (int tile = blockIdx.x; tile < ntiles; tile += gridDim.x) {
        const int r0 = tile * TR;
        __syncthreads();   // previous tile's readers done before overwrite
        for (int i = tid * 4; i < TR * K; i += 1024) {
            const int row = i / K;
            const int kk = i % K;
            float4 v;
            if (r0 + row < n) {
                v = *(const float4*)&X[(size_t)(r0 + row) * K + kk];
                if constexpr (AFF) {
                    v.x = fmaf(v.x, aff[kk],     aff[K + kk]);
                    v.y = fmaf(v.y, aff[kk + 1], aff[K + kk + 1]);
                    v.z = fmaf(v.z, aff[kk + 2], aff[K + kk + 2]);
                    v.w = fmaf(v.w, aff[kk + 3], aff[K + kk + 3]);
                }
            } else {
                v = make_float4(0.f, 0.f, 0.f, 0.f);
            }
            *(float4*)&sX[i] = v;
        }
        __syncthreads();   // also covers sW on first iteration

        float acc[RT][4];
        #pragma unroll
        for (int r = 0; r < RT; ++r)
            #pragma unroll
            for (int c = 0; c < 4; ++c) acc[r][c] = 0.0f;

        for (int k4 = 0; k4 < K; k4 += 4) {
            float xk[RT][4];
            #pragma unroll
            for (int r = 0; r < RT; ++r) {
                float4 t = *(const float4*)&sX[(ty * RT + r) * K + k4];
                xk[r][0] = t.x; xk[r][1] = t.y; xk[r][2] = t.z; xk[r][3] = t.w;
            }
            float4 wv[4];
            #pragma unroll
            for (int kk = 0; kk < 4; ++kk)
                wv[kk] = *(const float4*)&sW[(k4 + kk) * F + tx * 4];
            #pragma unroll
            for (int kk = 0; kk < 4; ++kk)
                #pragma unroll
                for (int r = 0; r < RT; ++r) {
                    const float xr = xk[r][kk];
                    acc[r][0] = fmaf(xr, wv[kk].x, acc[r][0]);
                    acc[r][1] = fmaf(xr, wv[kk].y, acc[r][1]);
                    acc[r][2] = fmaf(xr, wv[kk].z, acc[r][2]);
                    acc[r][3] = fmaf(xr, wv[kk].w, acc[r][3]);
                }
        }

        #pragma unroll
        for (int r = 0; r < RT; ++r) {
            const int row = r0 + ty * RT + r;
            if (row < n)
                *(float4*)&H[(size_t)row * F + tx * 4] =
                    make_float4(acc[r][0], acc[r][1], acc[r][2], acc[r][3]);
        }
    }
}

// ---------- CSR gather aggregation, fused self-loop + bias + ReLU + stats ----------
template<int F>
__global__ void k_aggf(const float* __restrict__ H, const int* __restrict__ rs,
                       const int* __restrict__ rend, const int* __restrict__ csrc,
                       const float* __restrict__ dinv, const float* __restrict__ b,
                       float* __restrict__ A, float* __restrict__ sums, int n) {
    const int f = threadIdx.x;
    const float bf = b[f];
    float ls = 0.0f, lq = 0.0f;
    for (int d = blockIdx.x; d < n; d += gridDim.x) {
        const int beg = rs[d];
        const int end = rend[d];
        const float di = dinv[d];
        float acc = H[(size_t)d * F + f] * di;    // self loop (x di again below)
        int j = beg;
        for (; j + 1 < end; j += 2) {
            int s0 = csrc[j], s1 = csrc[j + 1];
            float w0 = dinv[s0], w1 = dinv[s1];
            float h0 = H[(size_t)s0 * F + f], h1 = H[(size_t)s1 * F + f];
            acc = fmaf(h0, w0, acc);
            acc = fmaf(h1, w1, acc);
        }
        if (j < end) {
            int s = csrc[j];
            acc = fmaf(H[(size_t)s * F + f], dinv[s], acc);
        }
        float v = fmaxf(fmaf(acc, di, bf), 0.0f);
        A[(size_t)d * F + f] = v;
        ls += v;
        lq += v * v;
    }
    atomicAdd(&sums[f], ls);
    atomicAdd(&sums[F + f], lq);
}

// ---------- BN fold: aff = [a = rsqrt(var+eps)*g, c = be - mean*a] ----------
__global__ void k_bnprep(const float* __restrict__ sums, const float* __restrict__ g,
                         const float* __restrict__ be, float* __restrict__ aff,
                         int F, float invn) {
    int f = threadIdx.x;
    if (f < F) {
        float mean = sums[f] * invn;
        float var = sums[F + f] * invn - mean * mean;
        float a = rsqrtf(var + BN_EPS) * g[f];
        aff[f] = a;
        aff[F + f] = be[f] - mean * a;
    }
}

// ---------- final 64->2 GEMM with input affine ----------
__global__ void k_gemm4(const float* __restrict__ X, const float* __restrict__ W,
                        const float* __restrict__ aff, float* __restrict__ H, int n) {
    int i = blockIdx.x * blockDim.x + threadIdx.x;
    if (i >= n) return;
    float a0 = 0.0f, a1 = 0.0f;
    #pragma unroll 8
    for (int k = 0; k < 64; ++k) {
        float v = X[i * 64 + k] * aff[k] + aff[64 + k];
        a0 = fmaf(v, W[2 * k], a0);
        a1 = fmaf(v, W[2 * k + 1], a1);
    }
    H[2 * i] = a0;
    H[2 * i + 1] = a1;
}

// ---------- final aggregation (F=2) + bias + log_softmax, 1 thread/node ----------
__global__ void k_last(const float* __restrict__ H, const int* __restrict__ rs,
                       const int* __restrict__ rend, const int* __restrict__ csrc,
                       const float* __restrict__ dinv, const float* __restrict__ b,
                       float* __restrict__ out, int n) {
    int d = blockIdx.x * blockDim.x + threadIdx.x;
    if (d >= n) return;
    const float di = dinv[d];
    float a0 = H[2 * d] * di, a1 = H[2 * d + 1] * di;
    const int beg = rs[d], end = rend[d];
    for (int j = beg; j < end; ++j) {
        int s = csrc[j];
        float w = dinv[s];
        a0 = fmaf(H[2 * s], w, a0);
        a1 = fmaf(H[2 * s + 1], w, a1);
    }
    float v0 = fmaf(a0, di, b[0]);
    float v1 = fmaf(a1, di, b[1]);
    float m = fmaxf(v0, v1);
    float l = logf(expf(v0 - m) + expf(v1 - m)) + m;
    out[2 * d] = v0 - l;
    out[2 * d + 1] = v1 - l;
}

extern "C" void kernel_launch(void* const* d_in, const int* in_sizes, int n_in,
                              void* d_out, int out_size, void* d_ws, size_t ws_size,
                              hipStream_t stream) {
    const float* x   = (const float*)d_in[0];
    const int*   ei  = (const int*)d_in[1];
    const float* W1  = (const float*)d_in[2];
    const float* b1  = (const float*)d_in[3];
    const float* g1  = (const float*)d_in[4];
    const float* be1 = (const float*)d_in[5];
    const float* W2  = (const float*)d_in[6];
    const float* b2  = (const float*)d_in[7];
    const float* g2  = (const float*)d_in[8];
    const float* be2 = (const float*)d_in[9];
    const float* W3  = (const float*)d_in[10];
    const float* b3  = (const float*)d_in[11];
    const float* g3  = (const float*)d_in[12];
    const float* be3 = (const float*)d_in[13];
    const float* W4  = (const float*)d_in[14];
    const float* b4  = (const float*)d_in[15];
    float* out = (float*)d_out;

    const int N = in_sizes[0] / 24;
    const int E = in_sizes[1] / 2;
    const int* srcI = ei;
    const int* dstI = ei + E;

    // ---- workspace carve ----
    int* cnt   = (int*)d_ws;                 // N
    int* rs    = cnt + N;                    // N  (row start)
    int* cur   = rs + N;                     // N  (fill cursor -> row end)
    int* csrc  = cur + N;                    // E  (CSR src ids)
    int* bsum  = csrc + E;                   // 1024 (scan partials)
    float* dinv = (float*)(bsum + 1024);     // N
    float* H    = dinv + N;                  // N*128
    float* A    = H + (size_t)N * 128;       // N*128
    float* S    = A + (size_t)N * 128;       // 1280 stats
    float* sums1 = S,        *aff1 = S + 256;
    float* sums2 = S + 512,  *aff2 = S + 768;
    float* sums3 = S + 1024, *aff3 = S + 1152;

    hipMemsetAsync(S, 0, 1280 * sizeof(float), stream);

    const int TB = 256;
    const int nb = (N + 1023) / 1024;

    // ---- CSR build + dinv ----
    k_zero_i<<<(N + TB - 1) / TB, TB, 0, stream>>>(cnt, N);
    k_count<<<(E + TB - 1) / TB, TB, 0, stream>>>(dstI, cnt, E);
    k_dinv<<<(N + TB - 1) / TB, TB, 0, stream>>>(cnt, dinv, N);
    k_scan1<<<nb, 1024, 0, stream>>>(cnt, rs, bsum, N);
    k_scan2<<<1, 1024, 0, stream>>>(bsum, nb);
    k_scan3<<<(N + TB - 1) / TB, TB, 0, stream>>>(rs, cur, bsum, N);
    k_fill<<<(E + TB - 1) / TB, TB, 0, stream>>>(srcI, dstI, cur, csrc, E);
    // after k_fill, cur[d] == row end

    // ----- layer 1: 24 -> 128 -----
    k_gemm2<24, 128, 4, false><<<1024, 256, 0, stream>>>(x, W1, nullptr, H, N);
    k_aggf<128><<<4096, 128, 0, stream>>>(H, rs, cur, csrc, dinv, b1, A, sums1, N);
    k_bnprep<<<1, 128, 0, stream>>>(sums1, g1, be1, aff1, 128, 1.0f / (float)N);

    // ----- layer 2: 128 -> 128 -----
    k_gemm2<128, 128, 4, true><<<1024, 256, 0, stream>>>(A, W2, aff1, H, N);
    k_aggf<128><<<4096, 128, 0, stream>>>(H, rs, cur, csrc, dinv, b2, A, sums2, N);
    k_bnprep<<<1, 128, 0, stream>>>(sums2, g2, be2, aff2, 128, 1.0f / (float)N);

    // ----- layer 3: 128 -> 64 -----
    k_gemm2<128, 64, 2, true><<<1024, 256, 0, stream>>>(A, W3, aff2, H, N);
    k_aggf<64><<<4096, 64, 0, stream>>>(H, rs, cur, csrc, dinv, b3, A, sums3, N);
    k_bnprep<<<1, 64, 0, stream>>>(sums3, g3, be3, aff3, 64, 1.0f / (float)N);

    // ----- layer 4: 64 -> 2, log_softmax -----
    k_gemm4<<<(N + TB - 1) / TB, TB, 0, stream>>>(A, W4, aff3, H, N);
    k_last<<<(N + TB - 1) / TB, TB, 0, stream>>>(H, rs, cur, csrc, dinv, b4, out, N);
}